// Round 1
// baseline (386.533 us; speedup 1.0000x reference)
//
#include <hip/hip_runtime.h>
#include <hip/hip_bf16.h>

// CavAttention: B=2, L=5, H=100, W=176, C=256, HEADS=8, DH=32, inner=256
#define LQ 5
#define HQ 100
#define WQ 176
#define HWQ 17600      // HQ*WQ
#define TPB 16         // (b,h,w) tiles per block
#define ROWS 80        // TPB * LQ
#define NBLK 2200      // 2*HWQ / TPB
#define SCALE_QK 0.17677669529663687f

typedef __attribute__((ext_vector_type(8))) short bf16x8;
typedef __attribute__((ext_vector_type(4))) float f32x4;

__device__ __forceinline__ float bf2f(short s) {
  union { unsigned u; float f; } v;
  v.u = ((unsigned)(unsigned short)s) << 16;
  return v.f;
}
__device__ __forceinline__ unsigned short f2bf(float f) {
  union { float f; unsigned u; } v; v.f = f;
  unsigned r = (v.u + 0x7fffu + ((v.u >> 16) & 1u)) >> 16;
  return (unsigned short)r;
}

// ---- prologue: W_qkv (256x768) -> WqkvT (768x256) bf16; W_out (256x256) -> WoutT bf16
__global__ void prep_weights(const float* __restrict__ Wqkv,
                             const float* __restrict__ Wout,
                             unsigned short* __restrict__ WqkvT,
                             unsigned short* __restrict__ WoutT) {
  int idx = blockIdx.x * 256 + threadIdx.x;
  if (idx < 256 * 768) {
    int k = idx / 768, n = idx - k * 768;
    WqkvT[n * 256 + k] = f2bf(Wqkv[idx]);
  }
  if (idx < 256 * 256) {
    int k = idx >> 8, n = idx & 255;
    WoutT[n * 256 + k] = f2bf(Wout[idx]);
  }
}

// smem layout (bytes):
//   A_lds  [80][256] bf16 swizzled : 0      .. 40960
//   O_lds  [80][256] bf16 swizzled : 40960  .. 81920
//   QKV    [4][80][104] bf16       : 81920  .. 148480
//   gofs   [80] int                : 148480 .. 148800
//   maskv  [80] float              : 148800 .. 149120
#define SMEM_BYTES 149120

__global__ __launch_bounds__(256, 1)
void cav_attn_fused(const float* __restrict__ x,
                    const float* __restrict__ mask,
                    const unsigned short* __restrict__ WqkvT,
                    const unsigned short* __restrict__ WoutT,
                    const float* __restrict__ b_out,
                    float* __restrict__ out) {
  extern __shared__ char smem[];
  char* A_base = smem;
  char* O_base = smem + 40960;
  unsigned short* QKV = (unsigned short*)(smem + 81920);
  int*   gofs  = (int*)(smem + 148480);
  float* maskv = (float*)(smem + 148800);

  const int tid  = threadIdx.x;
  const int wave = tid >> 6;
  const int lane = tid & 63;
  const int lr   = lane & 15;   // fragment row (A) / col (B,D)
  const int lg   = lane >> 4;   // k-group (A,B) / row-group (D)
  const int tile0 = blockIdx.x * TPB;

  // per-row global offsets + mask values
  if (tid < ROWS) {
    int tt = tid / LQ;
    int l  = tid - tt * LQ;
    int gt = tile0 + tt;
    int b  = gt / HWQ;
    int rem = gt - b * HWQ;
    int h  = rem / WQ;
    int w  = rem - h * WQ;
    gofs[tid]  = (((b * LQ + l) * HQ + h) * WQ + w) << 8;
    maskv[tid] = mask[((b * HQ + h) * WQ + w) * LQ + l];
  }
  __syncthreads();

  // ---- P0: stage x tile -> A_lds (bf16, swizzled). wave w loads row i*4+w each iter.
  #pragma unroll
  for (int i = 0; i < 20; ++i) {
    int r  = i * 4 + wave;
    int kq = lane;                       // float4 index within row
    f32x4 v = *(const f32x4*)(x + gofs[r] + kq * 4);
    ushort4 pk;
    pk.x = f2bf(v[0]); pk.y = f2bf(v[1]); pk.z = f2bf(v[2]); pk.w = f2bf(v[3]);
    int byte = r * 512 + kq * 8;
    byte ^= (r & 7) << 4;
    *(ushort4*)(A_base + byte) = pk;
  }
  __syncthreads();

  unsigned short* qbuf = QKV + wave * (ROWS * 104);

  #pragma unroll 1
  for (int hi = 0; hi < 2; ++hi) {
    const int head = wave * 2 + hi;
    // ---- P1a: GEMM1 slice, 80 x 96 (q|k|v cols of this head)
    f32x4 acc[6][5];
    #pragma unroll
    for (int j = 0; j < 6; ++j)
      #pragma unroll
      for (int mt = 0; mt < 5; ++mt)
        acc[j][mt] = (f32x4){0.f, 0.f, 0.f, 0.f};

    const int hb = head * 32;
    const int nb[6] = { hb, hb + 16, 256 + hb, 256 + hb + 16, 512 + hb, 512 + hb + 16 };

    #pragma unroll
    for (int kt = 0; kt < 8; ++kt) {
      bf16x8 a[5];
      #pragma unroll
      for (int mt = 0; mt < 5; ++mt) {
        int row = mt * 16 + lr;
        int byte = row * 512 + kt * 64 + lg * 16;
        byte ^= (row & 7) << 4;
        a[mt] = *(const bf16x8*)(A_base + byte);
      }
      #pragma unroll
      for (int j = 0; j < 6; ++j) {
        bf16x8 bfr = *(const bf16x8*)(WqkvT + (nb[j] + lr) * 256 + kt * 32 + lg * 8);
        #pragma unroll
        for (int mt = 0; mt < 5; ++mt)
          acc[j][mt] = __builtin_amdgcn_mfma_f32_16x16x32_bf16(a[mt], bfr, acc[j][mt], 0, 0, 0);
      }
    }

    __syncthreads();  // protect previous iteration's qbuf readers before overwrite
    // ---- P1b: stage qkv (bf16) into per-wave LDS buffer [80][104]
    #pragma unroll
    for (int j = 0; j < 6; ++j)
      #pragma unroll
      for (int mt = 0; mt < 5; ++mt)
        #pragma unroll
        for (int rg = 0; rg < 4; ++rg) {
          int row = mt * 16 + lg * 4 + rg;   // D row = (lane>>4)*4 + reg
          qbuf[row * 104 + j * 16 + lr] = f2bf(acc[j][mt][rg]);
        }
    __syncthreads();

    // ---- P1c: attention. 4 lanes per tile (pass 0: rows 0..3; pass 1: row 4, lanes 0..15)
    #pragma unroll
    for (int ip = 0; ip < 2; ++ip) {
      const int t_ = (ip == 0) ? (lane >> 2) : lane;
      const int i_ = (ip == 0) ? (lane & 3) : 4;
      if (ip == 0 || lane < 16) {
        const int rq = t_ * 5 + i_;
        float q[32];
        #pragma unroll
        for (int ch = 0; ch < 4; ++ch) {
          bf16x8 qv = *(const bf16x8*)(qbuf + rq * 104 + ch * 8);
          #pragma unroll
          for (int e = 0; e < 8; ++e) q[ch * 8 + e] = bf2f(qv[e]);
        }
        float p[5];
        #pragma unroll
        for (int j = 0; j < 5; ++j) {
          const int rk = t_ * 5 + j;
          float d = 0.f;
          #pragma unroll
          for (int ch = 0; ch < 4; ++ch) {
            bf16x8 kv = *(const bf16x8*)(qbuf + rk * 104 + 32 + ch * 8);
            #pragma unroll
            for (int e = 0; e < 8; ++e) d += q[ch * 8 + e] * bf2f(kv[e]);
          }
          d *= SCALE_QK;
          p[j] = (maskv[rk] == 0.0f) ? -1e30f : d;
        }
        float mx = fmaxf(fmaxf(fmaxf(p[0], p[1]), fmaxf(p[2], p[3])), p[4]);
        float sum = 0.f;
        #pragma unroll
        for (int j = 0; j < 5; ++j) { p[j] = __expf(p[j] - mx); sum += p[j]; }
        const float inv = 1.0f / sum;
        float o[32];
        #pragma unroll
        for (int c = 0; c < 32; ++c) o[c] = 0.f;
        #pragma unroll
        for (int j = 0; j < 5; ++j) {
          const int rv = t_ * 5 + j;
          const float pj = p[j] * inv;
          #pragma unroll
          for (int ch = 0; ch < 4; ++ch) {
            bf16x8 vv = *(const bf16x8*)(qbuf + rv * 104 + 64 + ch * 8);
            #pragma unroll
            for (int e = 0; e < 8; ++e) o[ch * 8 + e] += pj * bf2f(vv[e]);
          }
        }
        // write o into O_lds (swizzled), cols head*32..+31
        #pragma unroll
        for (int ch = 0; ch < 8; ++ch) {
          ushort4 pk;
          pk.x = f2bf(o[ch * 4 + 0]); pk.y = f2bf(o[ch * 4 + 1]);
          pk.z = f2bf(o[ch * 4 + 2]); pk.w = f2bf(o[ch * 4 + 3]);
          int byte = rq * 512 + (head * 32 + ch * 4) * 2;
          byte ^= (rq & 7) << 4;
          *(ushort4*)(O_base + byte) = pk;
        }
      }
    }
  }
  __syncthreads();

  // ---- P2: out = O @ Wout + b_out. wave owns cols [wave*64, wave*64+64)
  f32x4 acc2[4][5];
  #pragma unroll
  for (int j = 0; j < 4; ++j)
    #pragma unroll
    for (int mt = 0; mt < 5; ++mt)
      acc2[j][mt] = (f32x4){0.f, 0.f, 0.f, 0.f};

  #pragma unroll
  for (int kt = 0; kt < 8; ++kt) {
    bf16x8 a[5];
    #pragma unroll
    for (int mt = 0; mt < 5; ++mt) {
      int row = mt * 16 + lr;
      int byte = row * 512 + kt * 64 + lg * 16;
      byte ^= (row & 7) << 4;
      a[mt] = *(const bf16x8*)(O_base + byte);
    }
    #pragma unroll
    for (int j = 0; j < 4; ++j) {
      bf16x8 bfr = *(const bf16x8*)(WoutT + (wave * 64 + j * 16 + lr) * 256 + kt * 32 + lg * 8);
      #pragma unroll
      for (int mt = 0; mt < 5; ++mt)
        acc2[j][mt] = __builtin_amdgcn_mfma_f32_16x16x32_bf16(a[mt], bfr, acc2[j][mt], 0, 0, 0);
    }
  }

  #pragma unroll
  for (int j = 0; j < 4; ++j) {
    const int col = wave * 64 + j * 16 + lr;
    const float bo = b_out[col];
    #pragma unroll
    for (int mt = 0; mt < 5; ++mt)
      #pragma unroll
      for (int rg = 0; rg < 4; ++rg) {
        int row = mt * 16 + lg * 4 + rg;
        out[gofs[row] + col] = acc2[j][mt][rg] + bo;
      }
  }
}

extern "C" void kernel_launch(void* const* d_in, const int* in_sizes, int n_in,
                              void* d_out, int out_size, void* d_ws, size_t ws_size,
                              hipStream_t stream) {
  (void)in_sizes; (void)n_in; (void)out_size; (void)ws_size;
  const float* x     = (const float*)d_in[0];
  const float* mask  = (const float*)d_in[1];
  const float* Wqkv  = (const float*)d_in[2];
  const float* Wout  = (const float*)d_in[3];
  const float* bout  = (const float*)d_in[4];
  float* out = (float*)d_out;

  // ws: WqkvT bf16 [768][256] (393216 B) + WoutT bf16 [256][256] (131072 B) = 524288 B
  unsigned short* WqkvT = (unsigned short*)d_ws;
  unsigned short* WoutT = WqkvT + 768 * 256;

  // allow >64KB dynamic LDS (no-op/ignored error if not needed on ROCm)
  (void)hipFuncSetAttribute((const void*)cav_attn_fused,
                            hipFuncAttributeMaxDynamicSharedMemorySize, SMEM_BYTES);

  prep_weights<<<768, 256, 0, stream>>>(Wqkv, Wout, WqkvT, WoutT);
  cav_attn_fused<<<NBLK, 256, SMEM_BYTES, stream>>>(x, mask, WqkvT, WoutT, bout, out);
}

// Round 2
// 345.153 us; speedup vs baseline: 1.1199x; 1.1199x over previous
//
#include <hip/hip_runtime.h>
#include <hip/hip_bf16.h>

// CavAttention: B=2, L=5, H=100, W=176, C=256, HEADS=8, DH=32, inner=256
#define LQ 5
#define HQ 100
#define WQ 176
#define HWQ 17600      // HQ*WQ
#define TPB 8          // (b,h,w) tiles per block
#define ROWS 40        // TPB * LQ
#define NBLK 4400      // 2*HWQ / TPB
#define SCALE_QK 0.17677669529663687f

// LDS layout (bytes):
//   A_lds  [40][512B] bf16 swizzled : 0     .. 20480   (mt=2 reads spill into O: benign)
//   O_lds  [40][512B] bf16 swizzled : 20480 .. 40960   (mt=2 reads spill into QKV: benign)
//   QKV    4 waves x [40][104] bf16 : 40960 .. 74240
//   gofs   [40] int                 : 74240 .. 74400
//   maskv  [40] float               : 74400 .. 74560
// epilogue overlays bytes 0..40960 with f32 [40][1024B] (after barrier; qbuf untouched)
#define A_OFF 0
#define O_OFF 20480
#define QKV_OFF 40960
#define QBUF_STRIDE 8320   // 40 * 104 shorts * 2B
#define GOFS_OFF 74240
#define MASK_OFF 74400
#define SMEM_BYTES 74560

typedef __attribute__((ext_vector_type(8))) short bf16x8;
typedef __attribute__((ext_vector_type(4))) float f32x4;

__device__ __forceinline__ float bf2f(short s) {
  union { unsigned u; float f; } v;
  v.u = ((unsigned)(unsigned short)s) << 16;
  return v.f;
}
__device__ __forceinline__ unsigned short f2bf(float f) {
  union { float f; unsigned u; } v; v.f = f;
  unsigned r = (v.u + 0x7fffu + ((v.u >> 16) & 1u)) >> 16;
  return (unsigned short)r;
}

// ---- prologue: W_qkv (256x768) -> WqkvT (768x256) bf16; W_out (256x256) -> WoutT bf16
__global__ void prep_weights(const float* __restrict__ Wqkv,
                             const float* __restrict__ Wout,
                             unsigned short* __restrict__ WqkvT,
                             unsigned short* __restrict__ WoutT) {
  int idx = blockIdx.x * 256 + threadIdx.x;
  if (idx < 256 * 768) {
    int k = idx / 768, n = idx - k * 768;
    WqkvT[n * 256 + k] = f2bf(Wqkv[idx]);
  }
  if (idx < 256 * 256) {
    int k = idx >> 8, n = idx & 255;
    WoutT[n * 256 + k] = f2bf(Wout[idx]);
  }
}

__global__ __launch_bounds__(256, 2)
void cav_attn_fused(const float* __restrict__ x,
                    const float* __restrict__ mask,
                    const unsigned short* __restrict__ WqkvT,
                    const unsigned short* __restrict__ WoutT,
                    const float* __restrict__ b_out,
                    float* __restrict__ out) {
  extern __shared__ char smem[];
  char* A_base = smem + A_OFF;
  char* O_base = smem + O_OFF;
  int*   gofs  = (int*)(smem + GOFS_OFF);
  float* maskv = (float*)(smem + MASK_OFF);

  const int tid  = threadIdx.x;
  const int wave = tid >> 6;
  const int lane = tid & 63;
  const int lr   = lane & 15;   // fragment row (A) / col (B,D)
  const int lg   = lane >> 4;   // k-group (A,B) / row-group (D)
  const int tile0 = blockIdx.x * TPB;

  // per-row global offsets + mask values
  if (tid < ROWS) {
    int tt = tid / LQ;
    int l  = tid - tt * LQ;
    int gt = tile0 + tt;
    int b  = gt / HWQ;
    int rem = gt - b * HWQ;
    int h  = rem / WQ;
    int w  = rem - h * WQ;
    gofs[tid]  = (((b * LQ + l) * HQ + h) * WQ + w) << 8;
    maskv[tid] = mask[((b * HQ + h) * WQ + w) * LQ + l];
  }
  __syncthreads();

  // ---- P0: stage x tile -> A_lds (bf16, swizzled). wave w loads row i*4+w.
  #pragma unroll
  for (int i = 0; i < 10; ++i) {
    int r  = i * 4 + wave;
    f32x4 v = *(const f32x4*)(x + gofs[r] + lane * 4);
    ushort4 pk;
    pk.x = f2bf(v[0]); pk.y = f2bf(v[1]); pk.z = f2bf(v[2]); pk.w = f2bf(v[3]);
    int byte = r * 512 + lane * 8;
    byte ^= (r & 7) << 4;
    *(ushort4*)(A_base + byte) = pk;
  }
  __syncthreads();

  unsigned short* qbuf = (unsigned short*)(smem + QKV_OFF + wave * QBUF_STRIDE);

  // ---- P1: per-head GEMM1 + attention. NO barriers inside (qbuf wave-private,
  //          A read-only, O writes per-wave-disjoint cols) -> waves free-run.
  #pragma unroll 1
  for (int hi = 0; hi < 2; ++hi) {
    const int head = wave * 2 + hi;
    // ---- P1a: GEMM1 slice, 40(48) x 96 (q|k|v cols of this head)
    f32x4 acc[6][3];
    #pragma unroll
    for (int j = 0; j < 6; ++j)
      #pragma unroll
      for (int mt = 0; mt < 3; ++mt)
        acc[j][mt] = (f32x4){0.f, 0.f, 0.f, 0.f};

    const int hb = head * 32;
    const int nb[6] = { hb, hb + 16, 256 + hb, 256 + hb + 16, 512 + hb, 512 + hb + 16 };

    #pragma unroll
    for (int kt = 0; kt < 8; ++kt) {
      bf16x8 a[3];
      #pragma unroll
      for (int mt = 0; mt < 3; ++mt) {
        int row = mt * 16 + lr;           // rows 40..47 read spill garbage (guarded later)
        int byte = row * 512 + kt * 64 + lg * 16;
        byte ^= (row & 7) << 4;
        a[mt] = *(const bf16x8*)(A_base + byte);
      }
      #pragma unroll
      for (int j = 0; j < 6; ++j) {
        bf16x8 bfr = *(const bf16x8*)(WqkvT + (nb[j] + lr) * 256 + kt * 32 + lg * 8);
        #pragma unroll
        for (int mt = 0; mt < 3; ++mt)
          acc[j][mt] = __builtin_amdgcn_mfma_f32_16x16x32_bf16(a[mt], bfr, acc[j][mt], 0, 0, 0);
      }
    }

    // ---- P1b: stage qkv (bf16) into wave-private LDS buffer [40][104]
    #pragma unroll
    for (int j = 0; j < 6; ++j)
      #pragma unroll
      for (int mt = 0; mt < 3; ++mt)
        #pragma unroll
        for (int rg = 0; rg < 4; ++rg) {
          int row = mt * 16 + lg * 4 + rg;   // D row = (lane>>4)*4 + reg
          if (row < ROWS)
            qbuf[row * 104 + j * 16 + lr] = f2bf(acc[j][mt][rg]);
        }

    // ---- P1c: attention, lanes 0..39 each own one (tile,row)
    if (lane < ROWS) {
      const int t_ = lane / 5;
      const int rq = lane;
      float q[32];
      #pragma unroll
      for (int ch = 0; ch < 4; ++ch) {
        bf16x8 qv = *(const bf16x8*)(qbuf + rq * 104 + ch * 8);
        #pragma unroll
        for (int e = 0; e < 8; ++e) q[ch * 8 + e] = bf2f(qv[e]);
      }
      float p[5];
      #pragma unroll
      for (int j = 0; j < 5; ++j) {
        const int rk = t_ * 5 + j;
        float d = 0.f;
        #pragma unroll
        for (int ch = 0; ch < 4; ++ch) {
          bf16x8 kv = *(const bf16x8*)(qbuf + rk * 104 + 32 + ch * 8);
          #pragma unroll
          for (int e = 0; e < 8; ++e) d += q[ch * 8 + e] * bf2f(kv[e]);
        }
        d *= SCALE_QK;
        p[j] = (maskv[rk] == 0.0f) ? -1e30f : d;
      }
      float mx = fmaxf(fmaxf(fmaxf(p[0], p[1]), fmaxf(p[2], p[3])), p[4]);
      float sum = 0.f;
      #pragma unroll
      for (int j = 0; j < 5; ++j) { p[j] = __expf(p[j] - mx); sum += p[j]; }
      const float inv = 1.0f / sum;
      float o[32];
      #pragma unroll
      for (int c = 0; c < 32; ++c) o[c] = 0.f;
      #pragma unroll
      for (int j = 0; j < 5; ++j) {
        const int rv = t_ * 5 + j;
        const float pj = p[j] * inv;
        #pragma unroll
        for (int ch = 0; ch < 4; ++ch) {
          bf16x8 vv = *(const bf16x8*)(qbuf + rv * 104 + 64 + ch * 8);
          #pragma unroll
          for (int e = 0; e < 8; ++e) o[ch * 8 + e] += pj * bf2f(vv[e]);
        }
      }
      // write o into O_lds (swizzled), cols head*32..+31
      #pragma unroll
      for (int ch = 0; ch < 8; ++ch) {
        ushort4 pk;
        pk.x = f2bf(o[ch * 4 + 0]); pk.y = f2bf(o[ch * 4 + 1]);
        pk.z = f2bf(o[ch * 4 + 2]); pk.w = f2bf(o[ch * 4 + 3]);
        int byte = rq * 512 + head * 64 + ch * 8;
        byte ^= (rq & 7) << 4;
        *(ushort4*)(O_base + byte) = pk;
      }
    }
  }
  __syncthreads();

  // ---- P2: out = O @ Wout + b_out. wave owns cols [wave*64, wave*64+64)
  f32x4 acc2[4][3];
  #pragma unroll
  for (int j = 0; j < 4; ++j)
    #pragma unroll
    for (int mt = 0; mt < 3; ++mt)
      acc2[j][mt] = (f32x4){0.f, 0.f, 0.f, 0.f};

  #pragma unroll
  for (int kt = 0; kt < 8; ++kt) {
    bf16x8 a[3];
    #pragma unroll
    for (int mt = 0; mt < 3; ++mt) {
      int row = mt * 16 + lr;             // rows 40..47 spill into qbuf region: benign
      int byte = row * 512 + kt * 64 + lg * 16;
      byte ^= (row & 7) << 4;
      a[mt] = *(const bf16x8*)(O_base + byte);
    }
    #pragma unroll
    for (int j = 0; j < 4; ++j) {
      bf16x8 bfr = *(const bf16x8*)(WoutT + (wave * 64 + j * 16 + lr) * 256 + kt * 32 + lg * 8);
      #pragma unroll
      for (int mt = 0; mt < 3; ++mt)
        acc2[j][mt] = __builtin_amdgcn_mfma_f32_16x16x32_bf16(a[mt], bfr, acc2[j][mt], 0, 0, 0);
    }
  }
  __syncthreads();   // all O_lds reads done before f32 overlay

  // ---- epilogue: stage f32 rows in LDS (bytes 0..40960), then coalesced 1KB-row stores
  #pragma unroll
  for (int j = 0; j < 4; ++j) {
    const int col = wave * 64 + j * 16 + lr;
    const float bo = b_out[col];
    #pragma unroll
    for (int mt = 0; mt < 3; ++mt)
      #pragma unroll
      for (int rg = 0; rg < 4; ++rg) {
        int row = mt * 16 + lg * 4 + rg;
        if (row < ROWS)
          *(float*)(smem + row * 1024 + col * 4) = acc2[j][mt][rg] + bo;
      }
  }
  __syncthreads();
  #pragma unroll
  for (int i = 0; i < 10; ++i) {
    int r = i * 4 + wave;
    f32x4 v = *(const f32x4*)(smem + r * 1024 + lane * 16);
    *(f32x4*)(out + gofs[r] + lane * 4) = v;
  }
}

extern "C" void kernel_launch(void* const* d_in, const int* in_sizes, int n_in,
                              void* d_out, int out_size, void* d_ws, size_t ws_size,
                              hipStream_t stream) {
  (void)in_sizes; (void)n_in; (void)out_size; (void)ws_size;
  const float* x     = (const float*)d_in[0];
  const float* mask  = (const float*)d_in[1];
  const float* Wqkv  = (const float*)d_in[2];
  const float* Wout  = (const float*)d_in[3];
  const float* bout  = (const float*)d_in[4];
  float* out = (float*)d_out;

  // ws: WqkvT bf16 [768][256] (393216 B) + WoutT bf16 [256][256] (131072 B)
  unsigned short* WqkvT = (unsigned short*)d_ws;
  unsigned short* WoutT = WqkvT + 768 * 256;

  (void)hipFuncSetAttribute((const void*)cav_attn_fused,
                            hipFuncAttributeMaxDynamicSharedMemorySize, SMEM_BYTES);

  prep_weights<<<768, 256, 0, stream>>>(Wqkv, Wout, WqkvT, WoutT);
  cav_attn_fused<<<NBLK, 256, SMEM_BYTES, stream>>>(x, mask, WqkvT, WoutT, bout, out);
}